// Round 7
// baseline (262.503 us; speedup 1.0000x reference)
//
#include <hip/hip_runtime.h>
#include <hip/hip_bf16.h>
#include <math.h>

#define NN 768
#define DD 64
#define SS 32
#define PP 4
#define NB2 1536   // k2 grid

#define MU_STEP   (12.0f / 31.0f)
#define INV2SIG2  3.55555555555f
#define NEG2C     (-INV2SIG2 * 1.4426950408889634f)

typedef __attribute__((ext_vector_type(8))) short bf16x8;
typedef __attribute__((ext_vector_type(4))) float f32x4;

__device__ __forceinline__ unsigned short f2bf(float f) {
    unsigned u = __float_as_uint(f);
    u += 0x7FFFu + ((u >> 16) & 1u);           // RNE
    return (unsigned short)(u >> 16);
}
__device__ __forceinline__ float bf2f(unsigned short b) {
    return __uint_as_float(((unsigned)b) << 16);
}

// ---------------------------------------------------------------------------
// kD (grid=3072): d[p][x][y] = sqrt(|coords[p][x]-coords[p][y]|^2 + 1e-12)
// ---------------------------------------------------------------------------
__global__ __launch_bounds__(256) void kD(const float* __restrict__ coords,
                                          float* __restrict__ dG,
                                          unsigned* __restrict__ ctr) {
    const int b = blockIdx.x;
    if (b == 0 && threadIdx.x == 0) *ctr = 0u;
    const int p = b / NN;
    const int x = b - p * NN;
    const float cxx = coords[((size_t)p * NN + x) * 3 + 0];
    const float cxy = coords[((size_t)p * NN + x) * 3 + 1];
    const float cxz = coords[((size_t)p * NN + x) * 3 + 2];
#pragma unroll
    for (int yb = 0; yb < 3; ++yb) {
        const int y = yb * 256 + threadIdx.x;
        const float dx = cxx - coords[((size_t)p * NN + y) * 3 + 0];
        const float dy = cxy - coords[((size_t)p * NN + y) * 3 + 1];
        const float dz = cxz - coords[((size_t)p * NN + y) * 3 + 2];
        dG[((size_t)p * NN + x) * NN + y] =
            sqrtf(fmaf(dx, dx, fmaf(dy, dy, fmaf(dz, dz, 1e-12f))));
    }
}

// ---------------------------------------------------------------------------
// Kernel 1 (grid=204): T + bf16 hi/lo A-fragments (unchanged, proven)
// ---------------------------------------------------------------------------
__global__ __launch_bounds__(256) void k1_T(const float* __restrict__ hid,
                                            const float* __restrict__ W,
                                            float* __restrict__ T,
                                            unsigned short* __restrict__ hbHi,
                                            unsigned short* __restrict__ hbLo) {
    const int b   = blockIdx.x;
    const int tid = threadIdx.x;

    __shared__ float hs[16 * 64];

    if (b < 192) {
        const int cb  = b & 3;
        const int xb  = b >> 2;
        const int c0  = cb * 512;
        const int x0  = xb * 16;
        const int ct  = tid & 63;
        const int xt  = tid >> 6;

        {
            const float4 v = *reinterpret_cast<const float4*>(&hid[(size_t)x0 * 64 + tid * 4]);
            *reinterpret_cast<float4*>(&hs[tid * 4]) = v;
        }
        __syncthreads();

        float acc[4][8];
#pragma unroll
        for (int m = 0; m < 4; ++m)
#pragma unroll
            for (int u = 0; u < 8; ++u) acc[m][u] = 0.0f;

        const int cbase = c0 + ct * 8;
#pragma unroll 4
        for (int i = 0; i < 64; ++i) {
            const float4 w0 = *reinterpret_cast<const float4*>(&W[(size_t)i * 2048 + cbase]);
            const float4 w1 = *reinterpret_cast<const float4*>(&W[(size_t)i * 2048 + cbase + 4]);
#pragma unroll
            for (int m = 0; m < 4; ++m) {
                const float hm = hs[(xt * 4 + m) * 64 + i];
                acc[m][0] += hm * w0.x; acc[m][1] += hm * w0.y;
                acc[m][2] += hm * w0.z; acc[m][3] += hm * w0.w;
                acc[m][4] += hm * w1.x; acc[m][5] += hm * w1.y;
                acc[m][6] += hm * w1.z; acc[m][7] += hm * w1.w;
            }
        }

#pragma unroll
        for (int m = 0; m < 4; ++m) {
            const int x = x0 + xt * 4 + m;
            float4 o0, o1;
            o0.x = acc[m][0]; o0.y = acc[m][1]; o0.z = acc[m][2]; o0.w = acc[m][3];
            o1.x = acc[m][4]; o1.y = acc[m][5]; o1.z = acc[m][6]; o1.w = acc[m][7];
            *reinterpret_cast<float4*>(&T[(size_t)x * 2048 + cbase])     = o0;
            *reinterpret_cast<float4*>(&T[(size_t)x * 2048 + cbase + 4]) = o1;
        }
    } else {
        const int base = (b - 192) * 4096 + tid * 16;   // flat (y*64+j)
        const int y  = base >> 6;
        const int j0 = base & 63;
        const int t  = y >> 4;
        const int r  = y & 15;
        float hv[16];
#pragma unroll
        for (int c = 0; c < 4; ++c) {
            const float4 v = *reinterpret_cast<const float4*>(&hid[(size_t)y * 64 + j0 + c * 4]);
            hv[c * 4 + 0] = v.x; hv[c * 4 + 1] = v.y; hv[c * 4 + 2] = v.z; hv[c * 4 + 3] = v.w;
        }
#pragma unroll
        for (int n = 0; n < 16; ++n) {
            const int j  = j0 + n;
            const int kh = j >> 5;
            const int g  = (j >> 3) & 3;
            const int e  = j & 7;
            const int idx = t * 1024 + kh * 512 + (g * 16 + r) * 8 + e;
            const unsigned short hi = f2bf(hv[n]);
            const float lo = hv[n] - bf2f(hi);
            hbHi[idx] = hi;
            hbLo[idx] = f2bf(lo);
        }
    }
}

// ---------------------------------------------------------------------------
// k2 ablation template.
//  V=0 : full kernel (R6-identical math; real output path)
//  V=1 : no dG loads (synthetic d)        — isolates dG stream latency
//  V=2 : no A-frag global loads (A:=B)    — isolates hb load latency
//  V=3 : no exp2 (w:=arg)                 — isolates transcendental cost
//  V=4 : no MFMA (acc from A-frag bits)   — isolates MFMA wait
//  V=6 : dd staged to LDS in prologue     — candidate fix, math == V0
// ---------------------------------------------------------------------------
template <int V>
__global__ __launch_bounds__(256, 2) void k2_abl(const float* __restrict__ b_rbf,
                                                 const float* __restrict__ Tg,
                                                 const unsigned short* __restrict__ hbHi,
                                                 const unsigned short* __restrict__ hbLo,
                                                 const float* __restrict__ dG,
                                                 float* __restrict__ partials,
                                                 unsigned* __restrict__ ctr,
                                                 const float* __restrict__ weight,
                                                 const float* __restrict__ bias_,
                                                 float* __restrict__ out) {
    const int bid = blockIdx.x;
    const int x   = bid >> 1;
    const int h   = bid & 1;
    const int tid = threadIdx.x;
    const int l   = tid & 63;
    const int wv  = tid >> 6;
    const int g   = l >> 4;
    const int c16 = l & 15;

    __shared__ unsigned short bh_s[2048];  // 4 KB  B-frag hi
    __shared__ unsigned short bl_s[2048];  // 4 KB  B-frag lo
    __shared__ float dd_s[(V == 6) ? PP * 384 : 4];  // 6 KB when staged
    __shared__ float red16[16];
    __shared__ unsigned flagS;

    // ---- prologue: T[x] -> bf16 hi/lo B-fragments in LDS ----
    {
        const float4 t0 = *reinterpret_cast<const float4*>(&Tg[(size_t)x * 2048 + tid * 8]);
        const float4 t1 = *reinterpret_cast<const float4*>(&Tg[(size_t)x * 2048 + tid * 8 + 4]);
        float tv[8];
        tv[0] = t0.x; tv[1] = t0.y; tv[2] = t0.z; tv[3] = t0.w;
        tv[4] = t1.x; tv[5] = t1.y; tv[6] = t1.z; tv[7] = t1.w;
        const int j    = tid >> 2;
        const int kh   = tid >> 7;
        const int jg   = (tid >> 5) & 3;
        const int e    = j & 7;
        const int st   = (tid >> 1) & 1;
        const int srb  = (tid & 1) * 8;
        const int base = (st * 2 + kh) * 512 + (jg * 16 + srb) * 8 + e;
#pragma unroll
        for (int q = 0; q < 8; ++q) {
            const unsigned short hi = f2bf(tv[q]);
            const float lo = tv[q] - bf2f(hi);
            bh_s[base + q * 8] = hi;
            bl_s[base + q * 8] = f2bf(lo);
        }
    }
    if constexpr (V == 6) {
        // stage this block's dd half-plane: 4 poses x 384 y = 6 KB
        for (int s = tid; s < PP * 96; s += 256) {
            const int p = s / 96, q = s - 96 * p;
            *reinterpret_cast<float4*>(&dd_s[p * 384 + q * 4]) =
                *reinterpret_cast<const float4*>(
                    &dG[(size_t)p * NN * NN + (size_t)x * NN + h * 384 + q * 4]);
        }
    }
    __syncthreads();

    const float mu0 = (float)(c16)      * MU_STEP;
    const float mu1 = (float)(16 + c16) * MU_STEP;
    const float A0 = -2.0f * NEG2C * mu0, B0v = NEG2C * mu0 * mu0;
    const float A1 = -2.0f * NEG2C * mu1, B1v = NEG2C * mu1 * mu1;
    const float brbf0 = b_rbf[c16];
    const float brbf1 = b_rbf[16 + c16];

    float e0 = 0.0f, e1 = 0.0f, e2 = 0.0f, e3 = 0.0f;

    for (int k = 0; k < 6; ++k) {
        const int t  = h * 24 + (k << 2) + wv;   // y-tile 0..47
        const int ab = t * 1024 + l * 8;
        const int yb = t * 16 + g * 4;
        const size_t dbase = (size_t)x * NN + yb;

        const bf16x8 bH00 = *reinterpret_cast<const bf16x8*>(&bh_s[l * 8]);
        const bf16x8 bH01 = *reinterpret_cast<const bf16x8*>(&bh_s[512 + l * 8]);
        const bf16x8 bH10 = *reinterpret_cast<const bf16x8*>(&bh_s[1024 + l * 8]);
        const bf16x8 bH11 = *reinterpret_cast<const bf16x8*>(&bh_s[1536 + l * 8]);
        const bf16x8 bL00 = *reinterpret_cast<const bf16x8*>(&bl_s[l * 8]);
        const bf16x8 bL01 = *reinterpret_cast<const bf16x8*>(&bl_s[512 + l * 8]);
        const bf16x8 bL10 = *reinterpret_cast<const bf16x8*>(&bl_s[1024 + l * 8]);
        const bf16x8 bL11 = *reinterpret_cast<const bf16x8*>(&bl_s[1536 + l * 8]);

        bf16x8 aH0, aH1, aL0, aL1;
        if constexpr (V != 2) {
            aH0 = *reinterpret_cast<const bf16x8*>(&hbHi[ab]);
            aH1 = *reinterpret_cast<const bf16x8*>(&hbHi[ab + 512]);
            aL0 = *reinterpret_cast<const bf16x8*>(&hbLo[ab]);
            aL1 = *reinterpret_cast<const bf16x8*>(&hbLo[ab + 512]);
        } else {
            aH0 = bH00; aH1 = bH01; aL0 = bL00; aL1 = bL01;
        }

        float4 dd0, dd1, dd2, dd3;
        if constexpr (V == 1) {
            const float base_d = (float)yb * 0.015f;
            dd0 = make_float4(base_d, base_d + 0.015f, base_d + 0.030f, base_d + 0.045f);
            dd1 = make_float4(dd0.x + 0.3f, dd0.y + 0.3f, dd0.z + 0.3f, dd0.w + 0.3f);
            dd2 = make_float4(dd0.x + 0.6f, dd0.y + 0.6f, dd0.z + 0.6f, dd0.w + 0.6f);
            dd3 = make_float4(dd0.x + 0.9f, dd0.y + 0.9f, dd0.z + 0.9f, dd0.w + 0.9f);
        } else if constexpr (V == 6) {
            const int lo = (t - h * 24) * 16 + g * 4;
            dd0 = *reinterpret_cast<const float4*>(&dd_s[0 * 384 + lo]);
            dd1 = *reinterpret_cast<const float4*>(&dd_s[1 * 384 + lo]);
            dd2 = *reinterpret_cast<const float4*>(&dd_s[2 * 384 + lo]);
            dd3 = *reinterpret_cast<const float4*>(&dd_s[3 * 384 + lo]);
        } else {
            dd0 = *reinterpret_cast<const float4*>(&dG[0 * (size_t)NN * NN + dbase]);
            dd1 = *reinterpret_cast<const float4*>(&dG[1 * (size_t)NN * NN + dbase]);
            dd2 = *reinterpret_cast<const float4*>(&dG[2 * (size_t)NN * NN + dbase]);
            dd3 = *reinterpret_cast<const float4*>(&dG[3 * (size_t)NN * NN + dbase]);
        }

        f32x4 acc0 = {0.0f, 0.0f, 0.0f, 0.0f};
        f32x4 acc1 = {0.0f, 0.0f, 0.0f, 0.0f};
        if constexpr (V != 4) {
            acc0 = __builtin_amdgcn_mfma_f32_16x16x32_bf16(aH0, bH00, acc0, 0, 0, 0);
            acc1 = __builtin_amdgcn_mfma_f32_16x16x32_bf16(aH0, bH10, acc1, 0, 0, 0);
            acc0 = __builtin_amdgcn_mfma_f32_16x16x32_bf16(aH1, bH01, acc0, 0, 0, 0);
            acc1 = __builtin_amdgcn_mfma_f32_16x16x32_bf16(aH1, bH11, acc1, 0, 0, 0);
            acc0 = __builtin_amdgcn_mfma_f32_16x16x32_bf16(aH0, bL00, acc0, 0, 0, 0);
            acc1 = __builtin_amdgcn_mfma_f32_16x16x32_bf16(aH0, bL10, acc1, 0, 0, 0);
            acc0 = __builtin_amdgcn_mfma_f32_16x16x32_bf16(aH1, bL01, acc0, 0, 0, 0);
            acc1 = __builtin_amdgcn_mfma_f32_16x16x32_bf16(aH1, bL11, acc1, 0, 0, 0);
            acc0 = __builtin_amdgcn_mfma_f32_16x16x32_bf16(aL0, bH00, acc0, 0, 0, 0);
            acc1 = __builtin_amdgcn_mfma_f32_16x16x32_bf16(aL0, bH10, acc1, 0, 0, 0);
            acc0 = __builtin_amdgcn_mfma_f32_16x16x32_bf16(aL1, bH01, acc0, 0, 0, 0);
            acc1 = __builtin_amdgcn_mfma_f32_16x16x32_bf16(aL1, bH11, acc1, 0, 0, 0);
        } else {
            // fabricate accs from A-frag bits (keeps A loads live, no MFMA)
            acc0[0] = bf2f((unsigned short)aH0[0]); acc0[1] = bf2f((unsigned short)aH0[1]);
            acc0[2] = bf2f((unsigned short)aH1[2]); acc0[3] = bf2f((unsigned short)aH1[3]);
            acc1[0] = bf2f((unsigned short)aL0[0]); acc1[1] = bf2f((unsigned short)aL0[1]);
            acc1[2] = bf2f((unsigned short)aL1[2]); acc1[3] = bf2f((unsigned short)aL1[3]);
        }

        const float ab00 = acc0[0] + brbf0, ab01 = acc0[1] + brbf0,
                    ab02 = acc0[2] + brbf0, ab03 = acc0[3] + brbf0;
        const float ab10 = acc1[0] + brbf1, ab11 = acc1[1] + brbf1,
                    ab12 = acc1[2] + brbf1, ab13 = acc1[3] + brbf1;

#pragma unroll
        for (int p = 0; p < PP; ++p) {
            const float4 dd = (p == 0) ? dd0 : (p == 1) ? dd1 : (p == 2) ? dd2 : dd3;
            float* ep = (p == 0) ? &e0 : (p == 1) ? &e1 : (p == 2) ? &e2 : &e3;
            float accp = 0.0f;
#pragma unroll
            for (int r = 0; r < 4; ++r) {
                if (yb + r == x) continue;     // diagonal mask
                const float d   = (r == 0) ? dd.x : (r == 1) ? dd.y : (r == 2) ? dd.z : dd.w;
                const float d2c = d * d * NEG2C;
                const float arg0 = fmaf(A0, d, d2c + B0v);
                const float arg1 = fmaf(A1, d, d2c + B1v);
                float w0, w1;
                if constexpr (V == 3) { w0 = arg0; w1 = arg1; }
                else { w0 = __builtin_exp2f(arg0); w1 = __builtin_exp2f(arg1); }
                const float a0 = (r == 0) ? ab00 : (r == 1) ? ab01 : (r == 2) ? ab02 : ab03;
                const float a1 = (r == 0) ? ab10 : (r == 1) ? ab11 : (r == 2) ? ab12 : ab13;
                accp = fmaf(a0, w0, accp);
                accp = fmaf(a1, w1, accp);
            }
            *ep += accp;
        }
    }

    // ---- deterministic reduction ----
    float e[PP] = {e0, e1, e2, e3};
#pragma unroll
    for (int off = 1; off < 64; off <<= 1)
#pragma unroll
        for (int p = 0; p < PP; ++p) e[p] += __shfl_xor(e[p], off, 64);

    if (l == 0) {
#pragma unroll
        for (int p = 0; p < PP; ++p) red16[wv * 4 + p] = e[p];
    }
    __syncthreads();
    if (tid < 4) {
        const float s = red16[0 * 4 + tid] + red16[1 * 4 + tid] +
                        red16[2 * 4 + tid] + red16[3 * 4 + tid];
        partials[(size_t)bid * 4 + tid] = s;
    }

    if constexpr (V == 0) {
        // ---- fused final reduction: last block sums all partials ----
        __threadfence();
        __syncthreads();
        if (tid == 0) {
            const unsigned old = atomicAdd(ctr, 1u);
            flagS = (old == NB2 - 1) ? 1u : 0u;
        }
        __syncthreads();
        if (flagS) {
            __threadfence();
            const int p    = tid >> 6;
            const int lane = tid & 63;
            float s = 0.0f;
#pragma unroll
            for (int kk = 0; kk < 24; ++kk)
                s += partials[(size_t)(lane * 24 + kk) * 4 + p];
#pragma unroll
            for (int off = 1; off < 64; off <<= 1) s += __shfl_xor(s, off, 64);
            if (lane == 0)
                out[p] = s * (1.0f / 18874368.0f) * weight[0] + bias_[0];
        }
    }
}

// ---------------------------------------------------------------------------
// Fallback path (ws too small): self-contained fp32 kernel + final reduce
// ---------------------------------------------------------------------------
__global__ __launch_bounds__(256, 4) void k2_fb(const float* __restrict__ hid,
                                                const float* __restrict__ coords,
                                                const float* __restrict__ W,
                                                const float* __restrict__ b_rbf,
                                                float* __restrict__ partials) {
    const int x   = blockIdx.x;
    const int tid = threadIdx.x;
    const int ty  = tid & 63;
    const int ts  = tid >> 6;

    __shared__ float pool[2048 + 64 * 128];
    float* T_l = pool;
    float* h_t = pool + 2048;

    {
        float a0[4] = {0, 0, 0, 0}, a1[4] = {0, 0, 0, 0};
        for (int i = 0; i < 64; ++i) {
            const float hv = hid[(size_t)x * 64 + i];
            const float4 w0 = *reinterpret_cast<const float4*>(&W[(size_t)i * 2048 + tid * 4]);
            const float4 w1 = *reinterpret_cast<const float4*>(&W[(size_t)i * 2048 + 1024 + tid * 4]);
            a0[0] += hv * w0.x; a0[1] += hv * w0.y; a0[2] += hv * w0.z; a0[3] += hv * w0.w;
            a1[0] += hv * w1.x; a1[1] += hv * w1.y; a1[2] += hv * w1.z; a1[3] += hv * w1.w;
        }
        T_l[tid * 4 + 0] = a0[0]; T_l[tid * 4 + 1] = a0[1];
        T_l[tid * 4 + 2] = a0[2]; T_l[tid * 4 + 3] = a0[3];
        T_l[1024 + tid * 4 + 0] = a1[0]; T_l[1024 + tid * 4 + 1] = a1[1];
        T_l[1024 + tid * 4 + 2] = a1[2]; T_l[1024 + tid * 4 + 3] = a1[3];
    }

    float mu_reg[8], b_reg[8];
#pragma unroll
    for (int u = 0; u < 8; ++u) {
        const int s = ts * 8 + u;
        mu_reg[u] = (float)s * MU_STEP;
        b_reg[u]  = b_rbf[s];
    }
    float cx[PP][3];
#pragma unroll
    for (int p = 0; p < PP; ++p)
#pragma unroll
        for (int c = 0; c < 3; ++c)
            cx[p][c] = coords[(size_t)p * NN * 3 + (size_t)x * 3 + c];

    float e[PP] = {0.0f, 0.0f, 0.0f, 0.0f};
    const int srow = tid >> 1;
    const int r0   = (tid & 1) * 8;
    const int hoff = ty * 2;
    const int toff = ts * 8;

    for (int ch = 0; ch < 6; ++ch) {
        const int y0 = ch * 128;
        __syncthreads();
        {
            const int y = y0 + srow;
#pragma unroll
            for (int r = 0; r < 8; ++r) {
                const float4 v = *reinterpret_cast<const float4*>(
                    &hid[(size_t)y * 64 + (r0 + r) * 4]);
                const int j = (r0 + r) * 4;
                h_t[(j + 0) * 128 + srow] = v.x;
                h_t[(j + 1) * 128 + srow] = v.y;
                h_t[(j + 2) * 128 + srow] = v.z;
                h_t[(j + 3) * 128 + srow] = v.w;
            }
        }
        __syncthreads();

        float acc[2][8];
#pragma unroll
        for (int i = 0; i < 2; ++i)
#pragma unroll
            for (int u = 0; u < 8; ++u) acc[i][u] = 0.0f;

#pragma unroll 4
        for (int j = 0; j < 64; ++j) {
            const float h0 = h_t[j * 128 + hoff];
            const float h1 = h_t[j * 128 + hoff + 1];
            const float4 t0 = *reinterpret_cast<const float4*>(&T_l[j * 32 + toff]);
            const float4 t1 = *reinterpret_cast<const float4*>(&T_l[j * 32 + toff + 4]);
            acc[0][0] += h0 * t0.x; acc[0][1] += h0 * t0.y; acc[0][2] += h0 * t0.z; acc[0][3] += h0 * t0.w;
            acc[0][4] += h0 * t1.x; acc[0][5] += h0 * t1.y; acc[0][6] += h0 * t1.z; acc[0][7] += h0 * t1.w;
            acc[1][0] += h1 * t0.x; acc[1][1] += h1 * t0.y; acc[1][2] += h1 * t0.z; acc[1][3] += h1 * t0.w;
            acc[1][4] += h1 * t1.x; acc[1][5] += h1 * t1.y; acc[1][6] += h1 * t1.z; acc[1][7] += h1 * t1.w;
        }

        float ab[2][8];
#pragma unroll
        for (int i = 0; i < 2; ++i)
#pragma unroll
            for (int u = 0; u < 8; ++u) ab[i][u] = acc[i][u] + b_reg[u];

#pragma unroll
        for (int i = 0; i < 2; ++i) {
            const int y = y0 + hoff + i;
            if (y == x) continue;
#pragma unroll
            for (int p = 0; p < PP; ++p) {
                const float dx = cx[p][0] - coords[(size_t)p * NN * 3 + (size_t)y * 3 + 0];
                const float dy = cx[p][1] - coords[(size_t)p * NN * 3 + (size_t)y * 3 + 1];
                const float dz = cx[p][2] - coords[(size_t)p * NN * 3 + (size_t)y * 3 + 2];
                const float d  = sqrtf(dx * dx + dy * dy + dz * dz + 1e-12f);
                float ep = 0.0f;
#pragma unroll
                for (int u = 0; u < 8; ++u) {
                    const float t = d - mu_reg[u];
                    const float w = __builtin_exp2f(t * t * NEG2C);
                    ep = fmaf(ab[i][u], w, ep);
                }
                e[p] += ep;
            }
        }
    }

#pragma unroll
    for (int off = 1; off < 64; off <<= 1)
#pragma unroll
        for (int p = 0; p < PP; ++p) e[p] += __shfl_xor(e[p], off, 64);

    __syncthreads();
    if (ty == 0) {
#pragma unroll
        for (int p = 0; p < PP; ++p) pool[ts * 4 + p] = e[p];
    }
    __syncthreads();
    if (tid < 4) {
        const float s = pool[0 * 4 + tid] + pool[1 * 4 + tid] +
                        pool[2 * 4 + tid] + pool[3 * 4 + tid];
        partials[(size_t)x * 4 + tid] = s;
    }
}

__global__ __launch_bounds__(256) void k3_final(const float* __restrict__ partials,
                                                const float* __restrict__ weight,
                                                const float* __restrict__ bias_,
                                                float* __restrict__ out) {
    const int p    = threadIdx.x >> 6;
    const int lane = threadIdx.x & 63;
    float s = 0.0f;
#pragma unroll
    for (int k = 0; k < 12; ++k) s += partials[(size_t)(lane * 12 + k) * 4 + p];
#pragma unroll
    for (int off = 1; off < 64; off <<= 1) s += __shfl_xor(s, off, 64);
    if (lane == 0)
        out[p] = s * (1.0f / 18874368.0f) * weight[0] + bias_[0];
}

// ---------------------------------------------------------------------------
extern "C" void kernel_launch(void* const* d_in, const int* in_sizes, int n_in,
                              void* d_out, int out_size, void* d_ws, size_t ws_size,
                              hipStream_t stream) {
    const float* hid    = (const float*)d_in[0];
    const float* coords = (const float*)d_in[1];
    const float* W      = (const float*)d_in[2];
    const float* b_rbf  = (const float*)d_in[3];
    const float* weight = (const float*)d_in[4];
    const float* bias_  = (const float*)d_in[5];
    float* out = (float*)d_out;

    const size_t T_BYTES    = (size_t)NN * 2048 * sizeof(float);          // 6.29 MB
    const size_t HB_BYTES   = (size_t)48 * 1024 * sizeof(unsigned short); // 96 KB/plane
    const size_t D_BYTES    = (size_t)PP * NN * NN * sizeof(float);       // 9.44 MB
    const size_t PART_BYTES = (size_t)NB2 * 4 * sizeof(float);            // 24.6 KB
    const size_t SCRAP_BYTES = PART_BYTES + 128;                          // ablation sink
    const size_t TOTAL = T_BYTES + 2 * HB_BYTES + D_BYTES + PART_BYTES + 64 + SCRAP_BYTES;
    const bool use_ws = ws_size >= TOTAL;

    char* w = (char*)d_ws;
    float*          Tg       = (float*)w;
    unsigned short* hbHi     = (unsigned short*)(w + T_BYTES);
    unsigned short* hbLo     = (unsigned short*)(w + T_BYTES + HB_BYTES);
    float*          dG       = (float*)(w + T_BYTES + 2 * HB_BYTES);
    float*          partials = use_ws ? (float*)(w + T_BYTES + 2 * HB_BYTES + D_BYTES)
                                      : (float*)d_ws;
    unsigned*       ctr      = (unsigned*)(w + T_BYTES + 2 * HB_BYTES + D_BYTES + PART_BYTES);
    float*          scrapP   = (float*)(w + T_BYTES + 2 * HB_BYTES + D_BYTES + PART_BYTES + 64);
    unsigned*       scrapC   = (unsigned*)(scrapP + NB2 * 4);
    float*          scrapO   = (float*)(scrapC + 4);

    if (use_ws) {
        kD<<<PP * NN, 256, 0, stream>>>(coords, dG, ctr);
        k1_T<<<204, 256, 0, stream>>>(hid, W, Tg, hbHi, hbLo);
        // ---- ablation dispatches (scrap output; diagnostic only) ----
        k2_abl<1><<<NB2, 256, 0, stream>>>(b_rbf, Tg, hbHi, hbLo, dG, scrapP, scrapC, weight, bias_, scrapO);
        k2_abl<2><<<NB2, 256, 0, stream>>>(b_rbf, Tg, hbHi, hbLo, dG, scrapP, scrapC, weight, bias_, scrapO);
        k2_abl<3><<<NB2, 256, 0, stream>>>(b_rbf, Tg, hbHi, hbLo, dG, scrapP, scrapC, weight, bias_, scrapO);
        k2_abl<4><<<NB2, 256, 0, stream>>>(b_rbf, Tg, hbHi, hbLo, dG, scrapP, scrapC, weight, bias_, scrapO);
        k2_abl<6><<<NB2, 256, 0, stream>>>(b_rbf, Tg, hbHi, hbLo, dG, scrapP, scrapC, weight, bias_, scrapO);
        // ---- real kernel (last; authoritative output) ----
        k2_abl<0><<<NB2, 256, 0, stream>>>(b_rbf, Tg, hbHi, hbLo, dG, partials, ctr, weight, bias_, out);
    } else {
        k2_fb<<<NN, 256, 0, stream>>>(hid, coords, W, b_rbf, partials);
        k3_final<<<1, 256, 0, stream>>>(partials, weight, bias_, out);
    }
}

// Round 8
// 152.062 us; speedup vs baseline: 1.7263x; 1.7263x over previous
//
#include <hip/hip_runtime.h>
#include <hip/hip_bf16.h>
#include <math.h>

#define NN 768
#define DD 64
#define SS 32
#define PP 4

#define MU_STEP   (12.0f / 31.0f)
#define INV2SIG2  3.55555555555f
#define NEG2C     (-INV2SIG2 * 1.4426950408889634f)

typedef __attribute__((ext_vector_type(8))) short bf16x8;
typedef __attribute__((ext_vector_type(4))) float f32x4;

__device__ __forceinline__ unsigned short f2bf(float f) {
    unsigned u = __float_as_uint(f);
    u += 0x7FFFu + ((u >> 16) & 1u);           // RNE
    return (unsigned short)(u >> 16);
}
__device__ __forceinline__ float bf2f(unsigned short b) {
    return __uint_as_float(((unsigned)b) << 16);
}

// ---------------------------------------------------------------------------
// k0 (grid=12, tiny): coordsT[(p*3+c)*768 + y] = coords[(p*768+y)*3 + c]
// (36 KB SoA so k2 can load 4 consecutive y as one aligned float4).
// Block 0 zeroes the last-block counter.
// ---------------------------------------------------------------------------
__global__ __launch_bounds__(256) void k0_prep(const float* __restrict__ coords,
                                               float* __restrict__ coordsT,
                                               unsigned* __restrict__ ctr) {
    const int b = blockIdx.x;          // b = p*3 + c
    if (b == 0 && threadIdx.x == 0) *ctr = 0u;
    const int p = b / 3;
    const int c = b - 3 * p;
#pragma unroll
    for (int yb = 0; yb < 3; ++yb) {
        const int y = yb * 256 + threadIdx.x;
        coordsT[(size_t)b * NN + y] = coords[((size_t)p * NN + y) * 3 + c];
    }
}

// ---------------------------------------------------------------------------
// k2 (grid=768, 512 thr = 8 waves, 2 blocks/CU): fully fused.
//  Reads ONLY immutable inputs (hid, coords, W, b_rbf) + 36 KB coordsT.
//  No cross-XCD dirty-line streams -> cold == warm (~22 us compute core).
//  prologue: T[x][c]=sum_i hid[x][i]*W[i][c] per thread (4 c's), split to
//            bf16 hi/lo B-fragments in LDS (verified R4/R6 layout).
//  loop: wave wv does tiles t = k*8+wv (48 tiles of 16 y-rows).
//    per tile: A-frags from hid (4xfloat4 + f2bf split, L2-hot),
//              dists from coordsT (12 float4, L1/L2-hot, 16-lane broadcast),
//              8 ds_read_b128 B-frags, 12 MFMA (proven order), rbf epilogue.
// ---------------------------------------------------------------------------
__global__ __launch_bounds__(512, 4) void k2_main(const float* __restrict__ hid,
                                                  const float* __restrict__ coords,
                                                  const float* __restrict__ W,
                                                  const float* __restrict__ b_rbf,
                                                  const float* __restrict__ coordsT,
                                                  float* __restrict__ partials,
                                                  unsigned* __restrict__ ctr,
                                                  const float* __restrict__ weight,
                                                  const float* __restrict__ bias_,
                                                  float* __restrict__ out) {
    const int x   = blockIdx.x;
    const int tid = threadIdx.x;
    const int l   = tid & 63;
    const int wv  = tid >> 6;          // 0..7
    const int g   = l >> 4;
    const int c16 = l & 15;

    __shared__ unsigned short bh_s[2048];  // 4 KB  B-frag hi
    __shared__ unsigned short bl_s[2048];  // 4 KB  B-frag lo
    __shared__ float red32[32];
    __shared__ unsigned flagS;

    // ---- prologue: T[x][c] for c = tid*4..+3, then hi/lo split to LDS ----
    {
        float a4[4] = {0.0f, 0.0f, 0.0f, 0.0f};
        const int cb = tid * 4;
        for (int i = 0; i < 64; ++i) {
            const float hv = hid[(size_t)x * 64 + i];   // block-uniform (s_load)
            const float4 w = *reinterpret_cast<const float4*>(&W[(size_t)i * 2048 + cb]);
            a4[0] = fmaf(hv, w.x, a4[0]);
            a4[1] = fmaf(hv, w.y, a4[1]);
            a4[2] = fmaf(hv, w.z, a4[2]);
            a4[3] = fmaf(hv, w.w, a4[3]);
        }
#pragma unroll
        for (int q = 0; q < 4; ++q) {
            const int c = cb + q;
            const int j = c >> 5;
            const int s = c & 31;
            const int idx = (s >> 4) * 1024 + (j >> 5) * 512 +
                            (((j >> 3) & 3) * 16 + (s & 15)) * 8 + (j & 7);
            const unsigned short hi = f2bf(a4[q]);
            const float lo = a4[q] - bf2f(hi);
            bh_s[idx] = hi;
            bl_s[idx] = f2bf(lo);
        }
    }
    __syncthreads();   // only barrier before reduction

    // per-lane rbf constants for s0 = c16 (acc0), s1 = 16+c16 (acc1)
    const float mu0 = (float)(c16)      * MU_STEP;
    const float mu1 = (float)(16 + c16) * MU_STEP;
    const float A0 = -2.0f * NEG2C * mu0, B0v = NEG2C * mu0 * mu0;
    const float A1 = -2.0f * NEG2C * mu1, B1v = NEG2C * mu1 * mu1;
    const float brbf0 = b_rbf[c16];
    const float brbf1 = b_rbf[16 + c16];

    // this block's x coordinates (uniform)
    float cxx[PP], cxy[PP], cxz[PP];
#pragma unroll
    for (int p = 0; p < PP; ++p) {
        cxx[p] = coords[((size_t)p * NN + x) * 3 + 0];
        cxy[p] = coords[((size_t)p * NN + x) * 3 + 1];
        cxz[p] = coords[((size_t)p * NN + x) * 3 + 2];
    }

    float e0 = 0.0f, e1 = 0.0f, e2 = 0.0f, e3 = 0.0f;

    for (int k = 0; k < 6; ++k) {
        const int t   = k * 8 + wv;        // y-tile 0..47
        const int row = t * 16 + c16;      // A-frag row for this lane
        const int yb4 = t * 16 + g * 4;    // epilogue rows for this lane

        // ---- A-frags from hid (raw loads) ----
        const int jb0 = g * 8;             // kh=0 half
        const int jb1 = 32 + g * 8;        // kh=1 half
        const float4 ha0 = *reinterpret_cast<const float4*>(&hid[(size_t)row * 64 + jb0]);
        const float4 ha1 = *reinterpret_cast<const float4*>(&hid[(size_t)row * 64 + jb0 + 4]);
        const float4 hb0 = *reinterpret_cast<const float4*>(&hid[(size_t)row * 64 + jb1]);
        const float4 hb1 = *reinterpret_cast<const float4*>(&hid[(size_t)row * 64 + jb1 + 4]);

        bf16x8 aH0, aL0, aH1, aL1;
        {
            float v[8];
            v[0] = ha0.x; v[1] = ha0.y; v[2] = ha0.z; v[3] = ha0.w;
            v[4] = ha1.x; v[5] = ha1.y; v[6] = ha1.z; v[7] = ha1.w;
#pragma unroll
            for (int q = 0; q < 8; ++q) {
                const unsigned short hi = f2bf(v[q]);
                aH0[q] = (short)hi;
                aL0[q] = (short)f2bf(v[q] - bf2f(hi));
            }
            v[0] = hb0.x; v[1] = hb0.y; v[2] = hb0.z; v[3] = hb0.w;
            v[4] = hb1.x; v[5] = hb1.y; v[6] = hb1.z; v[7] = hb1.w;
#pragma unroll
            for (int q = 0; q < 8; ++q) {
                const unsigned short hi = f2bf(v[q]);
                aH1[q] = (short)hi;
                aL1[q] = (short)f2bf(v[q] - bf2f(hi));
            }
        }

        // ---- distances for rows yb4..yb4+3, all 4 poses (16-lane broadcast) ----
        float4 dP[PP];
#pragma unroll
        for (int p = 0; p < PP; ++p) {
            const float4 X = *reinterpret_cast<const float4*>(&coordsT[(size_t)(p * 3 + 0) * NN + yb4]);
            const float4 Y = *reinterpret_cast<const float4*>(&coordsT[(size_t)(p * 3 + 1) * NN + yb4]);
            const float4 Z = *reinterpret_cast<const float4*>(&coordsT[(size_t)(p * 3 + 2) * NN + yb4]);
            float4 d;
            {
                const float dx0 = cxx[p] - X.x, dy0 = cxy[p] - Y.x, dz0 = cxz[p] - Z.x;
                const float dx1 = cxx[p] - X.y, dy1 = cxy[p] - Y.y, dz1 = cxz[p] - Z.y;
                const float dx2 = cxx[p] - X.z, dy2 = cxy[p] - Y.z, dz2 = cxz[p] - Z.z;
                const float dx3 = cxx[p] - X.w, dy3 = cxy[p] - Y.w, dz3 = cxz[p] - Z.w;
                d.x = sqrtf(fmaf(dx0, dx0, fmaf(dy0, dy0, fmaf(dz0, dz0, 1e-12f))));
                d.y = sqrtf(fmaf(dx1, dx1, fmaf(dy1, dy1, fmaf(dz1, dz1, 1e-12f))));
                d.z = sqrtf(fmaf(dx2, dx2, fmaf(dy2, dy2, fmaf(dz2, dz2, 1e-12f))));
                d.w = sqrtf(fmaf(dx3, dx3, fmaf(dy3, dy3, fmaf(dz3, dz3, 1e-12f))));
            }
            dP[p] = d;
        }

        // ---- B-frags (LDS, conflict-free b128) + 12 MFMA (proven order) ----
        const bf16x8 bH00 = *reinterpret_cast<const bf16x8*>(&bh_s[l * 8]);
        const bf16x8 bH01 = *reinterpret_cast<const bf16x8*>(&bh_s[512 + l * 8]);
        const bf16x8 bH10 = *reinterpret_cast<const bf16x8*>(&bh_s[1024 + l * 8]);
        const bf16x8 bH11 = *reinterpret_cast<const bf16x8*>(&bh_s[1536 + l * 8]);
        const bf16x8 bL00 = *reinterpret_cast<const bf16x8*>(&bl_s[l * 8]);
        const bf16x8 bL01 = *reinterpret_cast<const bf16x8*>(&bl_s[512 + l * 8]);
        const bf16x8 bL10 = *reinterpret_cast<const bf16x8*>(&bl_s[1024 + l * 8]);
        const bf16x8 bL11 = *reinterpret_cast<const bf16x8*>(&bl_s[1536 + l * 8]);

        f32x4 acc0 = {0.0f, 0.0f, 0.0f, 0.0f};
        f32x4 acc1 = {0.0f, 0.0f, 0.0f, 0.0f};
        acc0 = __builtin_amdgcn_mfma_f32_16x16x32_bf16(aH0, bH00, acc0, 0, 0, 0);
        acc1 = __builtin_amdgcn_mfma_f32_16x16x32_bf16(aH0, bH10, acc1, 0, 0, 0);
        acc0 = __builtin_amdgcn_mfma_f32_16x16x32_bf16(aH1, bH01, acc0, 0, 0, 0);
        acc1 = __builtin_amdgcn_mfma_f32_16x16x32_bf16(aH1, bH11, acc1, 0, 0, 0);
        acc0 = __builtin_amdgcn_mfma_f32_16x16x32_bf16(aH0, bL00, acc0, 0, 0, 0);
        acc1 = __builtin_amdgcn_mfma_f32_16x16x32_bf16(aH0, bL10, acc1, 0, 0, 0);
        acc0 = __builtin_amdgcn_mfma_f32_16x16x32_bf16(aH1, bL01, acc0, 0, 0, 0);
        acc1 = __builtin_amdgcn_mfma_f32_16x16x32_bf16(aH1, bL11, acc1, 0, 0, 0);
        acc0 = __builtin_amdgcn_mfma_f32_16x16x32_bf16(aL0, bH00, acc0, 0, 0, 0);
        acc1 = __builtin_amdgcn_mfma_f32_16x16x32_bf16(aL0, bH10, acc1, 0, 0, 0);
        acc0 = __builtin_amdgcn_mfma_f32_16x16x32_bf16(aL1, bH01, acc0, 0, 0, 0);
        acc1 = __builtin_amdgcn_mfma_f32_16x16x32_bf16(aL1, bH11, acc1, 0, 0, 0);

        // ---- rbf epilogue ----
        const float ab00 = acc0[0] + brbf0, ab01 = acc0[1] + brbf0,
                    ab02 = acc0[2] + brbf0, ab03 = acc0[3] + brbf0;
        const float ab10 = acc1[0] + brbf1, ab11 = acc1[1] + brbf1,
                    ab12 = acc1[2] + brbf1, ab13 = acc1[3] + brbf1;

#pragma unroll
        for (int p = 0; p < PP; ++p) {
            const float4 dd = dP[p];
            float* ep = (p == 0) ? &e0 : (p == 1) ? &e1 : (p == 2) ? &e2 : &e3;
            float accp = 0.0f;
#pragma unroll
            for (int r = 0; r < 4; ++r) {
                if (yb4 + r == x) continue;     // diagonal mask
                const float d   = (r == 0) ? dd.x : (r == 1) ? dd.y : (r == 2) ? dd.z : dd.w;
                const float d2c = d * d * NEG2C;
                const float w0 = __builtin_exp2f(fmaf(A0, d, d2c + B0v));
                const float w1 = __builtin_exp2f(fmaf(A1, d, d2c + B1v));
                const float a0 = (r == 0) ? ab00 : (r == 1) ? ab01 : (r == 2) ? ab02 : ab03;
                const float a1 = (r == 0) ? ab10 : (r == 1) ? ab11 : (r == 2) ? ab12 : ab13;
                accp = fmaf(a0, w0, accp);
                accp = fmaf(a1, w1, accp);
            }
            *ep += accp;
        }
    }

    // ---- deterministic reduction (8 waves) ----
    float e[PP] = {e0, e1, e2, e3};
#pragma unroll
    for (int off = 1; off < 64; off <<= 1)
#pragma unroll
        for (int p = 0; p < PP; ++p) e[p] += __shfl_xor(e[p], off, 64);

    if (l == 0) {
#pragma unroll
        for (int p = 0; p < PP; ++p) red32[wv * 4 + p] = e[p];
    }
    __syncthreads();
    if (tid < 4) {
        float s = 0.0f;
#pragma unroll
        for (int w8 = 0; w8 < 8; ++w8) s += red32[w8 * 4 + tid];
        partials[(size_t)x * 4 + tid] = s;
    }

    // ---- fused final reduction: last block sums all partials ----
    __threadfence();
    __syncthreads();
    if (tid == 0) {
        const unsigned old = atomicAdd(ctr, 1u);
        flagS = (old == NN - 1) ? 1u : 0u;
    }
    __syncthreads();
    if (flagS && tid < 256) {
        __threadfence();
        const int p    = tid >> 6;
        const int lane = tid & 63;
        float s = 0.0f;
#pragma unroll
        for (int kk = 0; kk < 12; ++kk)
            s += partials[(size_t)(lane * 12 + kk) * 4 + p];
#pragma unroll
        for (int off = 1; off < 64; off <<= 1) s += __shfl_xor(s, off, 64);
        if (lane == 0)
            out[p] = s * (1.0f / 18874368.0f) * weight[0] + bias_[0];
    }
}

// ---------------------------------------------------------------------------
// Fallback path (ws too small): self-contained fp32 kernel + final reduce
// ---------------------------------------------------------------------------
__global__ __launch_bounds__(256, 4) void k2_fb(const float* __restrict__ hid,
                                                const float* __restrict__ coords,
                                                const float* __restrict__ W,
                                                const float* __restrict__ b_rbf,
                                                float* __restrict__ partials) {
    const int x   = blockIdx.x;
    const int tid = threadIdx.x;
    const int ty  = tid & 63;
    const int ts  = tid >> 6;

    __shared__ float pool[2048 + 64 * 128];
    float* T_l = pool;
    float* h_t = pool + 2048;

    {
        float a0[4] = {0, 0, 0, 0}, a1[4] = {0, 0, 0, 0};
        for (int i = 0; i < 64; ++i) {
            const float hv = hid[(size_t)x * 64 + i];
            const float4 w0 = *reinterpret_cast<const float4*>(&W[(size_t)i * 2048 + tid * 4]);
            const float4 w1 = *reinterpret_cast<const float4*>(&W[(size_t)i * 2048 + 1024 + tid * 4]);
            a0[0] += hv * w0.x; a0[1] += hv * w0.y; a0[2] += hv * w0.z; a0[3] += hv * w0.w;
            a1[0] += hv * w1.x; a1[1] += hv * w1.y; a1[2] += hv * w1.z; a1[3] += hv * w1.w;
        }
        T_l[tid * 4 + 0] = a0[0]; T_l[tid * 4 + 1] = a0[1];
        T_l[tid * 4 + 2] = a0[2]; T_l[tid * 4 + 3] = a0[3];
        T_l[1024 + tid * 4 + 0] = a1[0]; T_l[1024 + tid * 4 + 1] = a1[1];
        T_l[1024 + tid * 4 + 2] = a1[2]; T_l[1024 + tid * 4 + 3] = a1[3];
    }

    float mu_reg[8], b_reg[8];
#pragma unroll
    for (int u = 0; u < 8; ++u) {
        const int s = ts * 8 + u;
        mu_reg[u] = (float)s * MU_STEP;
        b_reg[u]  = b_rbf[s];
    }
    float cx[PP][3];
#pragma unroll
    for (int p = 0; p < PP; ++p)
#pragma unroll
        for (int c = 0; c < 3; ++c)
            cx[p][c] = coords[(size_t)p * NN * 3 + (size_t)x * 3 + c];

    float e[PP] = {0.0f, 0.0f, 0.0f, 0.0f};
    const int srow = tid >> 1;
    const int r0   = (tid & 1) * 8;
    const int hoff = ty * 2;
    const int toff = ts * 8;

    for (int ch = 0; ch < 6; ++ch) {
        const int y0 = ch * 128;
        __syncthreads();
        {
            const int y = y0 + srow;
#pragma unroll
            for (int r = 0; r < 8; ++r) {
                const float4 v = *reinterpret_cast<const float4*>(
                    &hid[(size_t)y * 64 + (r0 + r) * 4]);
                const int j = (r0 + r) * 4;
                h_t[(j + 0) * 128 + srow] = v.x;
                h_t[(j + 1) * 128 + srow] = v.y;
                h_t[(j + 2) * 128 + srow] = v.z;
                h_t[(j + 3) * 128 + srow] = v.w;
            }
        }
        __syncthreads();

        float acc[2][8];
#pragma unroll
        for (int i = 0; i < 2; ++i)
#pragma unroll
            for (int u = 0; u < 8; ++u) acc[i][u] = 0.0f;

#pragma unroll 4
        for (int j = 0; j < 64; ++j) {
            const float h0 = h_t[j * 128 + hoff];
            const float h1 = h_t[j * 128 + hoff + 1];
            const float4 t0 = *reinterpret_cast<const float4*>(&T_l[j * 32 + toff]);
            const float4 t1 = *reinterpret_cast<const float4*>(&T_l[j * 32 + toff + 4]);
            acc[0][0] += h0 * t0.x; acc[0][1] += h0 * t0.y; acc[0][2] += h0 * t0.z; acc[0][3] += h0 * t0.w;
            acc[0][4] += h0 * t1.x; acc[0][5] += h0 * t1.y; acc[0][6] += h0 * t1.z; acc[0][7] += h0 * t1.w;
            acc[1][0] += h1 * t0.x; acc[1][1] += h1 * t0.y; acc[1][2] += h1 * t0.z; acc[1][3] += h1 * t0.w;
            acc[1][4] += h1 * t1.x; acc[1][5] += h1 * t1.y; acc[1][6] += h1 * t1.z; acc[1][7] += h1 * t1.w;
        }

        float ab[2][8];
#pragma unroll
        for (int i = 0; i < 2; ++i)
#pragma unroll
            for (int u = 0; u < 8; ++u) ab[i][u] = acc[i][u] + b_reg[u];

#pragma unroll
        for (int i = 0; i < 2; ++i) {
            const int y = y0 + hoff + i;
            if (y == x) continue;
#pragma unroll
            for (int p = 0; p < PP; ++p) {
                const float dx = cx[p][0] - coords[(size_t)p * NN * 3 + (size_t)y * 3 + 0];
                const float dy = cx[p][1] - coords[(size_t)p * NN * 3 + (size_t)y * 3 + 1];
                const float dz = cx[p][2] - coords[(size_t)p * NN * 3 + (size_t)y * 3 + 2];
                const float d  = sqrtf(dx * dx + dy * dy + dz * dz + 1e-12f);
                float ep = 0.0f;
#pragma unroll
                for (int u = 0; u < 8; ++u) {
                    const float t = d - mu_reg[u];
                    const float w = __builtin_exp2f(t * t * NEG2C);
                    ep = fmaf(ab[i][u], w, ep);
                }
                e[p] += ep;
            }
        }
    }

#pragma unroll
    for (int off = 1; off < 64; off <<= 1)
#pragma unroll
        for (int p = 0; p < PP; ++p) e[p] += __shfl_xor(e[p], off, 64);

    __syncthreads();
    if (ty == 0) {
#pragma unroll
        for (int p = 0; p < PP; ++p) pool[ts * 4 + p] = e[p];
    }
    __syncthreads();
    if (tid < 4) {
        const float s = pool[0 * 4 + tid] + pool[1 * 4 + tid] +
                        pool[2 * 4 + tid] + pool[3 * 4 + tid];
        partials[(size_t)x * 4 + tid] = s;
    }
}

__global__ __launch_bounds__(256) void k3_final(const float* __restrict__ partials,
                                                const float* __restrict__ weight,
                                                const float* __restrict__ bias_,
                                                float* __restrict__ out) {
    const int p    = threadIdx.x >> 6;
    const int lane = threadIdx.x & 63;
    float s = 0.0f;
#pragma unroll
    for (int k = 0; k < 12; ++k) s += partials[(size_t)(lane * 12 + k) * 4 + p];
#pragma unroll
    for (int off = 1; off < 64; off <<= 1) s += __shfl_xor(s, off, 64);
    if (lane == 0)
        out[p] = s * (1.0f / 18874368.0f) * weight[0] + bias_[0];
}

// ---------------------------------------------------------------------------
extern "C" void kernel_launch(void* const* d_in, const int* in_sizes, int n_in,
                              void* d_out, int out_size, void* d_ws, size_t ws_size,
                              hipStream_t stream) {
    const float* hid    = (const float*)d_in[0];
    const float* coords = (const float*)d_in[1];
    const float* W      = (const float*)d_in[2];
    const float* b_rbf  = (const float*)d_in[3];
    const float* weight = (const float*)d_in[4];
    const float* bias_  = (const float*)d_in[5];
    float* out = (float*)d_out;

    const size_t CT_BYTES   = (size_t)PP * 3 * NN * sizeof(float);   // 36 KB
    const size_t PART_BYTES = (size_t)NN * 4 * sizeof(float);        // 12 KB
    const size_t TOTAL = CT_BYTES + PART_BYTES + 64;
    const bool use_ws = ws_size >= TOTAL;

    char* w = (char*)d_ws;
    float*    coordsT  = (float*)w;
    float*    partials = use_ws ? (float*)(w + CT_BYTES) : (float*)d_ws;
    unsigned* ctr      = (unsigned*)(w + CT_BYTES + PART_BYTES);

    if (use_ws) {
        k0_prep<<<PP * 3, 256, 0, stream>>>(coords, coordsT, ctr);
        k2_main<<<NN, 512, 0, stream>>>(hid, coords, W, b_rbf, coordsT,
                                        partials, ctr, weight, bias_, out);
    } else {
        k2_fb<<<NN, 256, 0, stream>>>(hid, coords, W, b_rbf, partials);
        k3_final<<<1, 256, 0, stream>>>(partials, weight, bias_, out);
    }
}